// Round 10
// baseline (305.259 us; speedup 1.0000x reference)
//
#include <hip/hip_runtime.h>
#include <hip/hip_bf16.h>

#define FDIM 256
#define EDIM 64
#define LEAKY 0.2f

// MFMA GEMM tiling (round-8 proven config)
#define BM 128
#define BN 256
#define BK 32

#define SCAN_BLOCKS 64

typedef __attribute__((ext_vector_type(8))) short bfrag;   // 8 bf16 = 4 VGPR
typedef __attribute__((ext_vector_type(4))) float f4acc;   // 4 f32 accum

// fp32 -> bf16 bits, round-to-nearest-even
__device__ __forceinline__ unsigned f2bf(float x){
    unsigned u = __float_as_uint(x);
    return (u + 0x7FFFu + ((u >> 16) & 1u)) >> 16;
}
__device__ __forceinline__ float bf2f(unsigned b){
    return __uint_as_float(b << 16);
}
__device__ __forceinline__ unsigned pack_hi(float x, float y, float& hx, float& hy){
    unsigned bx = f2bf(x), by = f2bf(y);
    hx = bf2f(bx); hy = bf2f(by);
    return bx | (by << 16);
}
__device__ __forceinline__ unsigned pack_lo(float rx, float ry){
    return f2bf(rx) | (f2bf(ry) << 16);
}

// resident-grid barrier (grid must be <= #CUs so all blocks co-resident)
__device__ __forceinline__ void gbar(int* bar, int idx, int nb){
    __syncthreads();
    if (threadIdx.x == 0){
        __threadfence();
        atomicAdd(&bar[idx], 1);
        while (__hip_atomic_load(&bar[idx], __ATOMIC_ACQUIRE, __HIP_MEMORY_SCOPE_AGENT) < nb){}
        __threadfence();
    }
    __syncthreads();
}

// W (fp32 256x256) -> bf16 once; zero barrier flags
__global__ void k_wconv(const float* __restrict__ W, unsigned short* __restrict__ W16,
                        int* __restrict__ bar){
    int gt = blockIdx.x*256 + threadIdx.x;
    if (gt == 0){ bar[0] = 0; bar[1] = 0; }
    int i = gt*4;
    float4 v = *(const float4*)&W[i];
    uint2 o;
    o.x = f2bf(v.x) | (f2bf(v.y) << 16);
    o.y = f2bf(v.z) | (f2bf(v.w) << 16);
    *(uint2*)&W16[i] = o;
}

// MEGA kernel: blocks [0, nGemm) = split-bf16 MFMA GEMM (+fused s_src/s_dst);
// blocks [nGemm, ...) = per-edge ef.a_e dot (16 lanes/edge) + dst histogram.
// The two jobs are independent; grid fusion overlaps GEMM compute with the
// 204.8 MB ef HBM stream.
__global__ __launch_bounds__(256, 2) void k_mega(const float* __restrict__ h,
                                                 const unsigned short* __restrict__ W16,
                                                 const float* __restrict__ A,
                                                 unsigned short* __restrict__ z16,
                                                 float* __restrict__ s_src,
                                                 float* __restrict__ s_dst, int M, int nGemm,
                                                 const float* __restrict__ ef,
                                                 const int* __restrict__ dst,
                                                 float* __restrict__ edot,
                                                 int* __restrict__ counts, int E){
    __shared__ uint4 smA[BM*8];       // 16 KB
    __shared__ uint4 smB[BN*8];       // 32 KB
    __shared__ float sred[2][2][BM];  // 2 KB

    int tid = threadIdx.x;

    if ((int)blockIdx.x >= nGemm){
        // ---------------- ef-dot + histogram branch ----------------
        int bid = blockIdx.x - nGemm;
        int e = bid*16 + (tid >> 4);
        int l4 = tid & 15;
        if (e < E){
            float4 f  = *(const float4*)&ef[(size_t)e*EDIM + l4*4];
            float4 ae = *(const float4*)&A[2*FDIM + l4*4];
            float v = f.x*ae.x + f.y*ae.y + f.z*ae.z + f.w*ae.w;
            v += __shfl_xor(v, 8); v += __shfl_xor(v, 4);
            v += __shfl_xor(v, 2); v += __shfl_xor(v, 1);
            if (l4 == 0){
                edot[e] = v;
                atomicAdd(&counts[dst[e]], 1);
            }
        }
        return;
    }

    // ---------------- GEMM branch (round-8 structure) ----------------
    int m0 = blockIdx.x * BM;
    int wid  = tid >> 6;
    int lane = tid & 63;
    int wm = (wid >> 1) * 64;     // 0 / 64
    int wn = (wid & 1) * 128;     // 0 / 128
    int l15 = lane & 15;
    int l4  = lane >> 4;

    f4acc acc[4][8];
    #pragma unroll
    for (int i = 0; i < 4; ++i)
        #pragma unroll
        for (int j = 0; j < 8; ++j)
            acc[i][j] = (f4acc)(0.f);

    for (int kc = 0; kc < FDIM; kc += BK){
        #pragma unroll
        for (int q = 0; q < 6; ++q){
            int p = tid + q*256;
            if (p < 512){
                int row = p >> 2, k8 = p & 3;
                int gr = m0 + row;
                float4 v0, v1;
                if (gr < M){
                    const float* g = &h[(size_t)gr*FDIM + kc + k8*8];
                    v0 = *(const float4*)g; v1 = *(const float4*)(g + 4);
                } else {
                    v0 = make_float4(0.f,0.f,0.f,0.f); v1 = v0;
                }
                uint4 hi, lo; float hx, hy;
                hi.x = pack_hi(v0.x, v0.y, hx, hy);
                lo.x = pack_lo(v0.x - hx, v0.y - hy);
                hi.y = pack_hi(v0.z, v0.w, hx, hy);
                lo.y = pack_lo(v0.z - hx, v0.w - hy);
                hi.z = pack_hi(v1.x, v1.y, hx, hy);
                lo.z = pack_lo(v1.x - hx, v1.y - hy);
                hi.w = pack_hi(v1.z, v1.w, hx, hy);
                lo.w = pack_lo(v1.z - hx, v1.w - hy);
                int sh = k8 ^ (row & 7);
                smA[row*8 + sh]       = hi;
                smA[row*8 + (sh ^ 4)] = lo;
            } else {
                int pb = p - 512;
                int row = pb >> 2, k8 = pb & 3;
                uint4 v = *(const uint4*)&W16[(size_t)row*FDIM + kc + k8*8];
                smB[row*8 + (k8 ^ (row & 7))] = v;
            }
        }
        __syncthreads();

        bfrag ah[4], al[4];
        #pragma unroll
        for (int mf = 0; mf < 4; ++mf){
            int row = wm + mf*16 + l15;
            int sh = l4 ^ (row & 7);
            ah[mf] = *(const bfrag*)&smA[row*8 + sh];
            al[mf] = *(const bfrag*)&smA[row*8 + (sh ^ 4)];
        }
        #pragma unroll
        for (int nf = 0; nf < 8; ++nf){
            int row = wn + nf*16 + l15;
            bfrag bh = *(const bfrag*)&smB[row*8 + (l4 ^ (row & 7))];
            #pragma unroll
            for (int mf = 0; mf < 4; ++mf){
                acc[mf][nf] = __builtin_amdgcn_mfma_f32_16x16x32_bf16(ah[mf], bh, acc[mf][nf], 0, 0, 0);
                acc[mf][nf] = __builtin_amdgcn_mfma_f32_16x16x32_bf16(al[mf], bh, acc[mf][nf], 0, 0, 0);
            }
        }
        __syncthreads();
    }

    // z write (bf16)
    #pragma unroll
    for (int mf = 0; mf < 4; ++mf){
        #pragma unroll
        for (int nf = 0; nf < 8; ++nf){
            int gcol = wn + nf*16 + l15;
            #pragma unroll
            for (int r = 0; r < 4; ++r){
                int grow = m0 + wm + mf*16 + l4*4 + r;
                if (grow < M)
                    z16[(size_t)grow*FDIM + gcol] = (unsigned short)f2bf(acc[mf][nf][r]);
            }
        }
    }

    // fused s_src / s_dst (complete per block, direct store)
    float aS[8], aD[8];
    #pragma unroll
    for (int nf = 0; nf < 8; ++nf){
        int gcol = wn + nf*16 + l15;
        aS[nf] = A[gcol];
        aD[nf] = A[FDIM + gcol];
    }
    #pragma unroll
    for (int mf = 0; mf < 4; ++mf){
        #pragma unroll
        for (int r = 0; r < 4; ++r){
            float ps = 0.f, pd = 0.f;
            #pragma unroll
            for (int nf = 0; nf < 8; ++nf){
                ps += acc[mf][nf][r] * aS[nf];
                pd += acc[mf][nf][r] * aD[nf];
            }
            #pragma unroll
            for (int o = 1; o < 16; o <<= 1){
                ps += __shfl_xor(ps, o);
                pd += __shfl_xor(pd, o);
            }
            if (l15 == 0){
                int row = wm + mf*16 + l4*4 + r;
                sred[wid & 1][0][row] = ps;
                sred[wid & 1][1][row] = pd;
            }
        }
    }
    __syncthreads();
    if (tid < BM){
        int grow = m0 + tid;
        if (grow < M){
            s_src[grow] = sred[0][0][tid] + sred[1][0][tid];
            s_dst[grow] = sred[0][1][tid] + sred[1][1][tid];
        }
    }
}

// fused 3-phase scan: counts -> exclusive offsets (+cursor copy), one launch
__global__ __launch_bounds__(256) void k_scan(int* __restrict__ counts, int* __restrict__ cursor,
                                              int* __restrict__ bsums, int* __restrict__ bar,
                                              int N, int E){
    __shared__ int sh[256];
    int tid = threadIdx.x;
    int chunk = (N + SCAN_BLOCKS - 1) / SCAN_BLOCKS;
    int c0 = blockIdx.x * chunk;
    int lim = min(c0 + chunk, N);

    int s = 0;
    for (int i = c0 + tid; i < lim; i += 256) s += counts[i];
    sh[tid] = s; __syncthreads();
    for (int o = 128; o > 0; o >>= 1){
        if (tid < o) sh[tid] += sh[tid + o];
        __syncthreads();
    }
    if (tid == 0) bsums[blockIdx.x] = sh[0];

    gbar(bar, 0, SCAN_BLOCKS);

    if (blockIdx.x == 0 && tid < 64){
        int v = bsums[tid];
        int orig = v;
        #pragma unroll
        for (int o = 1; o < 64; o <<= 1){
            int t = __shfl_up(v, o);
            if (tid >= o) v += t;
        }
        bsums[tid] = v - orig;
    }

    gbar(bar, 1, SCAN_BLOCKS);

    int base = c0 + tid*4;
    int v[4]; int ts = 0;
    #pragma unroll
    for (int l = 0; l < 4; l++){
        int idx = base + l;
        v[l] = (idx < lim) ? counts[idx] : 0;
        ts += v[l];
    }
    __syncthreads();
    sh[tid] = ts; __syncthreads();
    int acc = ts;
    for (int o = 1; o < 256; o <<= 1){
        int t = (tid >= o) ? sh[tid - o] : 0;
        __syncthreads();
        acc += t; sh[tid] = acc;
        __syncthreads();
    }
    int excl = acc - ts + bsums[blockIdx.x];
    #pragma unroll
    for (int l = 0; l < 4; l++){
        int idx = base + l;
        if (idx < lim){ counts[idx] = excl; cursor[idx] = excl; }
        excl += v[l];
    }
    if (blockIdx.x == 0 && tid == 0) counts[N] = E;
}

// per-edge finalize: logit = edot + s_src[src] + s_dst[dst], leaky, counting-sort
__global__ void k_edge2(const float* __restrict__ edot,
                        const float* __restrict__ s_src, const float* __restrict__ s_dst,
                        const int* __restrict__ src, const int* __restrict__ dst,
                        int* __restrict__ cursor, int2* __restrict__ epair, int E){
    int e = blockIdx.x*256 + threadIdx.x;
    if (e >= E) return;
    int sN = src[e], dN = dst[e];
    float lg = edot[e] + s_src[sN] + s_dst[dN];
    lg = lg > 0.f ? lg : LEAKY*lg;
    int p = atomicAdd(&cursor[dN], 1);
    int2 pr; pr.x = sN; pr.y = __float_as_int(lg);
    epair[p] = pr;
}

// final: 4 dst nodes per block, one wave per node; coalesced epair + shfl
__global__ __launch_bounds__(256) void k_out(const unsigned short* __restrict__ z16,
                                             const int* __restrict__ offsets,
                                             const int2* __restrict__ epair,
                                             float* __restrict__ out, int N){
    int n = blockIdx.x*4 + (threadIdx.x >> 6);
    int lane = threadIdx.x & 63;
    if (n >= N) return;
    int i0 = offsets[n], i1 = offsets[n+1];

    float mlane = -3.402823466e38f;
    for (int i = i0 + lane; i < i1; i += 64)
        mlane = fmaxf(mlane, __int_as_float(epair[i].y));
    float mx = mlane;
    #pragma unroll
    for (int o = 32; o > 0; o >>= 1)
        mx = fmaxf(mx, __shfl_xor(mx, o));

    float4 a[4];
    a[0] = make_float4(0,0,0,0); a[1] = a[0]; a[2] = a[0]; a[3] = a[0];
    float dw = 0.f;
    const unsigned short* zb = z16 + lane*4;

    for (int base = i0; base < i1; base += 64){
        int cnt = min(64, i1 - base);
        int2 pe = make_int2(0, 0);
        float w = 0.f;
        if (lane < cnt){
            pe = epair[base + lane];
            w = __expf(__int_as_float(pe.y) - mx);
        }
        dw += w;
        int j = 0;
        for (; j + 7 < cnt; j += 8){
            float wj[8]; int sj[8]; uint2 rj[8];
            #pragma unroll
            for (int q = 0; q < 8; ++q){
                wj[q] = __shfl(w, j + q);
                sj[q] = __shfl(pe.x, j + q);
            }
            #pragma unroll
            for (int q = 0; q < 8; ++q)
                rj[q] = *(const uint2*)&zb[(size_t)sj[q]*FDIM];
            #pragma unroll
            for (int q = 0; q < 8; ++q){
                a[q & 3].x += wj[q]*bf2f(rj[q].x & 0xffffu);
                a[q & 3].y += wj[q]*bf2f(rj[q].x >> 16);
                a[q & 3].z += wj[q]*bf2f(rj[q].y & 0xffffu);
                a[q & 3].w += wj[q]*bf2f(rj[q].y >> 16);
            }
        }
        for (; j < cnt; ++j){
            float wq = __shfl(w, j);
            int   sq = __shfl(pe.x, j);
            uint2 r0 = *(const uint2*)&zb[(size_t)sq*FDIM];
            a[0].x += wq*bf2f(r0.x & 0xffffu);
            a[0].y += wq*bf2f(r0.x >> 16);
            a[0].z += wq*bf2f(r0.y & 0xffffu);
            a[0].w += wq*bf2f(r0.y >> 16);
        }
    }

    #pragma unroll
    for (int o = 32; o > 0; o >>= 1)
        dw += __shfl_xor(dw, o);

    float inv = (i1 > i0) ? 1.f / dw : 0.f;
    float4 res;
    res.x = ((a[0].x + a[1].x) + (a[2].x + a[3].x)) * inv;
    res.y = ((a[0].y + a[1].y) + (a[2].y + a[3].y)) * inv;
    res.z = ((a[0].z + a[1].z) + (a[2].z + a[3].z)) * inv;
    res.w = ((a[0].w + a[1].w) + (a[2].w + a[3].w)) * inv;
    *(float4*)&out[(size_t)n*FDIM + lane*4] = res;
}

extern "C" void kernel_launch(void* const* d_in, const int* in_sizes, int n_in,
                              void* d_out, int out_size, void* d_ws, size_t ws_size,
                              hipStream_t stream){
    const float* h  = (const float*)d_in[0];
    const float* ef = (const float*)d_in[1];
    const float* W  = (const float*)d_in[2];
    const float* A  = (const float*)d_in[3];
    const int*  src = (const int*)d_in[4];
    const int*  dst = (const int*)d_in[5];
    float* out = (float*)d_out;
    int N = in_sizes[0] / FDIM;
    int E = in_sizes[4];

    char* ws = (char*)d_ws;
    size_t off = 0;
    auto alloc = [&](size_t nbytes)->char*{
        char* p = ws + off;
        off = (off + nbytes + 255) & ~(size_t)255;
        return p;
    };
    unsigned short* z16 = (unsigned short*)alloc((size_t)N*FDIM*2);
    unsigned short* W16 = (unsigned short*)alloc((size_t)FDIM*FDIM*2);
    float* s_src  = (float*)alloc((size_t)N*4);
    float* s_dst  = (float*)alloc((size_t)N*4);
    float* edot   = (float*)alloc((size_t)E*4);
    int*   counts = (int*)alloc((size_t)(N+1)*4);
    int*   cursor = (int*)alloc((size_t)N*4);
    int2*  epair  = (int2*)alloc((size_t)E*8);
    int*   bsums  = (int*)alloc(SCAN_BLOCKS*4);
    int*   bar    = (int*)alloc(2*4);

    int nGemm = (N + BM - 1) / BM;
    int nEf   = (E + 15) / 16;

    hipMemsetAsync(counts, 0, (size_t)(N+1)*4, stream);
    hipLaunchKernelGGL(k_wconv, dim3(64), dim3(256), 0, stream, W, W16, bar);
    hipLaunchKernelGGL(k_mega, dim3(nGemm + nEf), dim3(256), 0, stream,
                       h, W16, A, z16, s_src, s_dst, N, nGemm,
                       ef, dst, edot, counts, E);
    hipLaunchKernelGGL(k_scan, dim3(SCAN_BLOCKS), dim3(256), 0, stream,
                       counts, cursor, bsums, bar, N, E);
    hipLaunchKernelGGL(k_edge2, dim3((E+255)/256), dim3(256), 0, stream,
                       edot, s_src, s_dst, src, dst, cursor, epair, E);
    hipLaunchKernelGGL(k_out, dim3((N+3)/4), dim3(256), 0, stream,
                       z16, counts, epair, out, N);
}

// Round 12
// 233.576 us; speedup vs baseline: 1.3069x; 1.3069x over previous
//
#include <hip/hip_runtime.h>
#include <hip/hip_bf16.h>

#define FDIM 256
#define EDIM 64
#define LEAKY 0.2f

// MFMA GEMM tiling (round-8 proven config)
#define BM 128
#define BN 256
#define BK 32

#define SCAN_BLOCKS 64

typedef __attribute__((ext_vector_type(8))) short bfrag;   // 8 bf16 = 4 VGPR
typedef __attribute__((ext_vector_type(4))) float f4acc;   // 4 f32 accum

// fp32 -> bf16 bits, round-to-nearest-even
__device__ __forceinline__ unsigned f2bf(float x){
    unsigned u = __float_as_uint(x);
    return (u + 0x7FFFu + ((u >> 16) & 1u)) >> 16;
}
__device__ __forceinline__ float bf2f(unsigned b){
    return __uint_as_float(b << 16);
}
__device__ __forceinline__ unsigned pack_hi(float x, float y, float& hx, float& hy){
    unsigned bx = f2bf(x), by = f2bf(y);
    hx = bf2f(bx); hy = bf2f(by);
    return bx | (by << 16);
}
__device__ __forceinline__ unsigned pack_lo(float rx, float ry){
    return f2bf(rx) | (f2bf(ry) << 16);
}

// async global->LDS copy, 16 bytes per lane (wave-uniform LDS base + lane*16)
__device__ __forceinline__ void gload16(void* lds, const void* g){
    __builtin_amdgcn_global_load_lds(
        (const __attribute__((address_space(1))) unsigned int*)g,
        (__attribute__((address_space(3))) unsigned int*)lds, 16, 0, 0);
}

// resident-grid barrier (grid <= #CUs so all blocks co-resident)
__device__ __forceinline__ void gbar(int* bar, int idx, int nb){
    __syncthreads();
    if (threadIdx.x == 0){
        __threadfence();
        atomicAdd(&bar[idx], 1);
        while (__hip_atomic_load(&bar[idx], __ATOMIC_ACQUIRE, __HIP_MEMORY_SCOPE_AGENT) < nb){}
        __threadfence();
    }
    __syncthreads();
}

// W conversion + dst histogram + barrier-flag zeroing, one pass
__global__ void k_prep(const float* __restrict__ W, unsigned short* __restrict__ W16,
                       const int* __restrict__ dst, int* __restrict__ counts,
                       int* __restrict__ bar, int E){
    int gt = blockIdx.x*256 + threadIdx.x;
    if (gt == 0){ bar[0] = 0; bar[1] = 0; }
    if (gt < (FDIM*FDIM)/4){
        int i = gt*4;
        float4 v = *(const float4*)&W[i];
        uint2 o;
        o.x = f2bf(v.x) | (f2bf(v.y) << 16);
        o.y = f2bf(v.z) | (f2bf(v.w) << 16);
        *(uint2*)&W16[i] = o;
    }
    if (gt < E) atomicAdd(&counts[dst[gt]], 1);
}

// z = h @ W^T via split-bf16 MFMA: A = hi+lo (in-kernel), B = bf16 pre-converted,
// staged via global_load_lds (pre-swizzled source, linear LDS dest, ALL 2048 slots).
__global__ __launch_bounds__(256, 2) void k_gemm(const float* __restrict__ h,
                                                 const unsigned short* __restrict__ W16,
                                                 const float* __restrict__ A,
                                                 unsigned short* __restrict__ z16,
                                                 float* __restrict__ s_src,
                                                 float* __restrict__ s_dst, int M){
    __shared__ uint4 smA[BM*8];       // 16 KB
    __shared__ uint4 smB[BN*8];       // 32 KB
    __shared__ float sred[2][2][BM];  // 2 KB

    int tid = threadIdx.x;
    int m0 = blockIdx.x * BM;

    int wid  = tid >> 6;
    int lane = tid & 63;
    int wm = (wid >> 1) * 64;     // 0 / 64
    int wn = (wid & 1) * 128;     // 0 / 128
    int l15 = lane & 15;
    int l4  = lane >> 4;

    f4acc acc[4][8];
    #pragma unroll
    for (int i = 0; i < 4; ++i)
        #pragma unroll
        for (int j = 0; j < 8; ++j)
            acc[i][j] = (f4acc)(0.f);

    for (int kc = 0; kc < FDIM; kc += BK){
        // ---- B staging: async direct-to-LDS over ALL 2048 slots (8/thread).
        // Slot s expects data k8 = (s&7) ^ (row&7); dead slots (k8>=4) fetch a
        // harmless duplicate (k8&3) from L2-resident W16.
        #pragma unroll
        for (int q = 0; q < 8; ++q){
            int s = tid + q*256;
            int row = s >> 3;
            int k8 = (s & 7) ^ (row & 7);
            const unsigned short* g = &W16[(size_t)row*FDIM + kc + (k8 & 3)*8];
            gload16(&smB[s], g);
        }
        // ---- A staging: fp32 -> hi/lo bf16 conversion in regs, swizzled ds_write
        #pragma unroll
        for (int q = 0; q < 2; ++q){
            int p = tid + q*256;
            int row = p >> 2, k8 = p & 3;
            int gr = m0 + row;
            float4 v0, v1;
            if (gr < M){
                const float* g = &h[(size_t)gr*FDIM + kc + k8*8];
                v0 = *(const float4*)g; v1 = *(const float4*)(g + 4);
            } else {
                v0 = make_float4(0.f,0.f,0.f,0.f); v1 = v0;
            }
            uint4 hi, lo; float hx, hy;
            hi.x = pack_hi(v0.x, v0.y, hx, hy);
            lo.x = pack_lo(v0.x - hx, v0.y - hy);
            hi.y = pack_hi(v0.z, v0.w, hx, hy);
            lo.y = pack_lo(v0.z - hx, v0.w - hy);
            hi.z = pack_hi(v1.x, v1.y, hx, hy);
            lo.z = pack_lo(v1.x - hx, v1.y - hy);
            hi.w = pack_hi(v1.z, v1.w, hx, hy);
            lo.w = pack_lo(v1.z - hx, v1.w - hy);
            int sh = k8 ^ (row & 7);
            smA[row*8 + sh]       = hi;
            smA[row*8 + (sh ^ 4)] = lo;
        }
        __syncthreads();

        bfrag ah[4], al[4];
        #pragma unroll
        for (int mf = 0; mf < 4; ++mf){
            int row = wm + mf*16 + l15;
            int sh = l4 ^ (row & 7);
            ah[mf] = *(const bfrag*)&smA[row*8 + sh];
            al[mf] = *(const bfrag*)&smA[row*8 + (sh ^ 4)];
        }
        #pragma unroll
        for (int nf = 0; nf < 8; ++nf){
            int row = wn + nf*16 + l15;
            bfrag bh = *(const bfrag*)&smB[row*8 + (l4 ^ (row & 7))];
            #pragma unroll
            for (int mf = 0; mf < 4; ++mf){
                acc[mf][nf] = __builtin_amdgcn_mfma_f32_16x16x32_bf16(ah[mf], bh, acc[mf][nf], 0, 0, 0);
                acc[mf][nf] = __builtin_amdgcn_mfma_f32_16x16x32_bf16(al[mf], bh, acc[mf][nf], 0, 0, 0);
            }
        }
        __syncthreads();
    }

    // ---- z write (bf16) ----
    #pragma unroll
    for (int mf = 0; mf < 4; ++mf){
        #pragma unroll
        for (int nf = 0; nf < 8; ++nf){
            int gcol = wn + nf*16 + l15;
            #pragma unroll
            for (int r = 0; r < 4; ++r){
                int grow = m0 + wm + mf*16 + l4*4 + r;
                if (grow < M)
                    z16[(size_t)grow*FDIM + gcol] = (unsigned short)f2bf(acc[mf][nf][r]);
            }
        }
    }

    // ---- fused s_src / s_dst (complete per block, direct store) ----
    float aS[8], aD[8];
    #pragma unroll
    for (int nf = 0; nf < 8; ++nf){
        int gcol = wn + nf*16 + l15;
        aS[nf] = A[gcol];
        aD[nf] = A[FDIM + gcol];
    }
    #pragma unroll
    for (int mf = 0; mf < 4; ++mf){
        #pragma unroll
        for (int r = 0; r < 4; ++r){
            float ps = 0.f, pd = 0.f;
            #pragma unroll
            for (int nf = 0; nf < 8; ++nf){
                ps += acc[mf][nf][r] * aS[nf];
                pd += acc[mf][nf][r] * aD[nf];
            }
            #pragma unroll
            for (int o = 1; o < 16; o <<= 1){
                ps += __shfl_xor(ps, o);
                pd += __shfl_xor(pd, o);
            }
            if (l15 == 0){
                int row = wm + mf*16 + l4*4 + r;
                sred[wid & 1][0][row] = ps;
                sred[wid & 1][1][row] = pd;
            }
        }
    }
    __syncthreads();
    if (tid < BM){
        int grow = m0 + tid;
        if (grow < M){
            s_src[grow] = sred[0][0][tid] + sred[1][0][tid];
            s_dst[grow] = sred[0][1][tid] + sred[1][1][tid];
        }
    }
}

// fused 3-phase scan: counts -> exclusive offsets (+cursor copy), one launch
__global__ __launch_bounds__(256) void k_scan(int* __restrict__ counts, int* __restrict__ cursor,
                                              int* __restrict__ bsums, int* __restrict__ bar,
                                              int N, int E){
    __shared__ int sh[256];
    int tid = threadIdx.x;
    int chunk = (N + SCAN_BLOCKS - 1) / SCAN_BLOCKS;
    int c0 = blockIdx.x * chunk;
    int lim = min(c0 + chunk, N);

    int s = 0;
    for (int i = c0 + tid; i < lim; i += 256) s += counts[i];
    sh[tid] = s; __syncthreads();
    for (int o = 128; o > 0; o >>= 1){
        if (tid < o) sh[tid] += sh[tid + o];
        __syncthreads();
    }
    if (tid == 0) bsums[blockIdx.x] = sh[0];

    gbar(bar, 0, SCAN_BLOCKS);

    if (blockIdx.x == 0 && tid < 64){
        int v = bsums[tid];
        int orig = v;
        #pragma unroll
        for (int o = 1; o < 64; o <<= 1){
            int t = __shfl_up(v, o);
            if (tid >= o) v += t;
        }
        bsums[tid] = v - orig;
    }

    gbar(bar, 1, SCAN_BLOCKS);

    int base = c0 + tid*4;
    int v[4]; int ts = 0;
    #pragma unroll
    for (int l = 0; l < 4; l++){
        int idx = base + l;
        v[l] = (idx < lim) ? counts[idx] : 0;
        ts += v[l];
    }
    __syncthreads();
    sh[tid] = ts; __syncthreads();
    int acc = ts;
    for (int o = 1; o < 256; o <<= 1){
        int t = (tid >= o) ? sh[tid - o] : 0;
        __syncthreads();
        acc += t; sh[tid] = acc;
        __syncthreads();
    }
    int excl = acc - ts + bsums[blockIdx.x];
    #pragma unroll
    for (int l = 0; l < 4; l++){
        int idx = base + l;
        if (idx < lim){ counts[idx] = excl; cursor[idx] = excl; }
        excl += v[l];
    }
    if (blockIdx.x == 0 && tid == 0) counts[N] = E;
}

// per-edge: e_feat dot + logit + leaky-relu + counting-sort write {src, logit}
__global__ void k_edge(const float* __restrict__ ef, const float* __restrict__ A,
                       const float* __restrict__ s_src, const float* __restrict__ s_dst,
                       const int* __restrict__ src, const int* __restrict__ dst,
                       int* __restrict__ cursor, int2* __restrict__ epair, int E){
    int gt = blockIdx.x*256 + threadIdx.x;
    int e = gt >> 4, l4 = gt & 15;
    if (e >= E) return;
    float4 f  = *(const float4*)&ef[(size_t)e*EDIM + l4*4];
    float4 ae = *(const float4*)&A[2*FDIM + l4*4];
    float v = f.x*ae.x + f.y*ae.y + f.z*ae.z + f.w*ae.w;
    v += __shfl_xor(v, 8); v += __shfl_xor(v, 4);
    v += __shfl_xor(v, 2); v += __shfl_xor(v, 1);
    if (l4 == 0){
        int d = dst[e];
        float lg = v + s_src[src[e]] + s_dst[d];
        lg = lg > 0.f ? lg : LEAKY*lg;
        int p = atomicAdd(&cursor[d], 1);
        int2 pr; pr.x = src[e]; pr.y = __float_as_int(lg);
        epair[p] = pr;
    }
}

// final: 4 dst nodes per block, one wave per node; coalesced epair + shfl
__global__ __launch_bounds__(256) void k_out(const unsigned short* __restrict__ z16,
                                             const int* __restrict__ offsets,
                                             const int2* __restrict__ epair,
                                             float* __restrict__ out, int N){
    int n = blockIdx.x*4 + (threadIdx.x >> 6);
    int lane = threadIdx.x & 63;
    if (n >= N) return;
    int i0 = offsets[n], i1 = offsets[n+1];

    float mlane = -3.402823466e38f;
    for (int i = i0 + lane; i < i1; i += 64)
        mlane = fmaxf(mlane, __int_as_float(epair[i].y));
    float mx = mlane;
    #pragma unroll
    for (int o = 32; o > 0; o >>= 1)
        mx = fmaxf(mx, __shfl_xor(mx, o));

    float4 a[4];
    a[0] = make_float4(0,0,0,0); a[1] = a[0]; a[2] = a[0]; a[3] = a[0];
    float dw = 0.f;
    const unsigned short* zb = z16 + lane*4;

    for (int base = i0; base < i1; base += 64){
        int cnt = min(64, i1 - base);
        int2 pe = make_int2(0, 0);
        float w = 0.f;
        if (lane < cnt){
            pe = epair[base + lane];
            w = __expf(__int_as_float(pe.y) - mx);
        }
        dw += w;
        int j = 0;
        for (; j + 7 < cnt; j += 8){
            float wj[8]; int sj[8]; uint2 rj[8];
            #pragma unroll
            for (int q = 0; q < 8; ++q){
                wj[q] = __shfl(w, j + q);
                sj[q] = __shfl(pe.x, j + q);
            }
            #pragma unroll
            for (int q = 0; q < 8; ++q)
                rj[q] = *(const uint2*)&zb[(size_t)sj[q]*FDIM];
            #pragma unroll
            for (int q = 0; q < 8; ++q){
                a[q & 3].x += wj[q]*bf2f(rj[q].x & 0xffffu);
                a[q & 3].y += wj[q]*bf2f(rj[q].x >> 16);
                a[q & 3].z += wj[q]*bf2f(rj[q].y & 0xffffu);
                a[q & 3].w += wj[q]*bf2f(rj[q].y >> 16);
            }
        }
        for (; j < cnt; ++j){
            float wq = __shfl(w, j);
            int   sq = __shfl(pe.x, j);
            uint2 r0 = *(const uint2*)&zb[(size_t)sq*FDIM];
            a[0].x += wq*bf2f(r0.x & 0xffffu);
            a[0].y += wq*bf2f(r0.x >> 16);
            a[0].z += wq*bf2f(r0.y & 0xffffu);
            a[0].w += wq*bf2f(r0.y >> 16);
        }
    }

    #pragma unroll
    for (int o = 32; o > 0; o >>= 1)
        dw += __shfl_xor(dw, o);

    float inv = (i1 > i0) ? 1.f / dw : 0.f;
    float4 res;
    res.x = ((a[0].x + a[1].x) + (a[2].x + a[3].x)) * inv;
    res.y = ((a[0].y + a[1].y) + (a[2].y + a[3].y)) * inv;
    res.z = ((a[0].z + a[1].z) + (a[2].z + a[3].z)) * inv;
    res.w = ((a[0].w + a[1].w) + (a[2].w + a[3].w)) * inv;
    *(float4*)&out[(size_t)n*FDIM + lane*4] = res;
}

extern "C" void kernel_launch(void* const* d_in, const int* in_sizes, int n_in,
                              void* d_out, int out_size, void* d_ws, size_t ws_size,
                              hipStream_t stream){
    const float* h  = (const float*)d_in[0];
    const float* ef = (const float*)d_in[1];
    const float* W  = (const float*)d_in[2];
    const float* A  = (const float*)d_in[3];
    const int*  src = (const int*)d_in[4];
    const int*  dst = (const int*)d_in[5];
    float* out = (float*)d_out;
    int N = in_sizes[0] / FDIM;
    int E = in_sizes[4];

    char* ws = (char*)d_ws;
    size_t off = 0;
    auto alloc = [&](size_t nbytes)->char*{
        char* p = ws + off;
        off = (off + nbytes + 255) & ~(size_t)255;
        return p;
    };
    unsigned short* z16 = (unsigned short*)alloc((size_t)N*FDIM*2);
    unsigned short* W16 = (unsigned short*)alloc((size_t)FDIM*FDIM*2);
    float* s_src  = (float*)alloc((size_t)N*4);
    float* s_dst  = (float*)alloc((size_t)N*4);
    int*   counts = (int*)alloc((size_t)(N+1)*4);
    int*   cursor = (int*)alloc((size_t)N*4);
    int2*  epair  = (int2*)alloc((size_t)E*8);
    int*   bsums  = (int*)alloc(SCAN_BLOCKS*4);
    int*   bar    = (int*)alloc(2*4);

    hipMemsetAsync(counts, 0, (size_t)(N+1)*4, stream);
    hipLaunchKernelGGL(k_prep, dim3((E+255)/256), dim3(256), 0, stream,
                       W, W16, dst, counts, bar, E);
    hipLaunchKernelGGL(k_gemm, dim3((N+BM-1)/BM), dim3(256), 0, stream,
                       h, W16, A, z16, s_src, s_dst, N);
    hipLaunchKernelGGL(k_scan, dim3(SCAN_BLOCKS), dim3(256), 0, stream,
                       counts, cursor, bsums, bar, N, E);
    hipLaunchKernelGGL(k_edge, dim3((E+15)/16), dim3(256), 0, stream,
                       ef, A, s_src, s_dst, src, dst, cursor, epair, E);
    hipLaunchKernelGGL(k_out, dim3((N+3)/4), dim3(256), 0, stream,
                       z16, counts, epair, out, N);
}